// Round 1
// baseline (70130.676 us; speedup 1.0000x reference)
//
#include <hip/hip_runtime.h>
#include <cstdint>
#include <cstddef>

// VQ nearest-codebook, two-phase:
//   P1: fp16 MFMA approx scores -> per-row candidate set (superset, margin-sound)
//   P2 (rewritten this round): latency-bound per-row rescore replaced with
//       select (singleton rows decided free) -> dense (row,code) pair worklist
//       -> packed u64 atomicMin argmin -> coalesced gather.
constexpr int N_ROWS = 32768;
constexpr int KCODES = 8192;
constexpr int DIMS   = 512;
constexpr int CAND   = 32;
constexpr float MARGIN = 1e-3f;   // bound |q'-q_np| ~1.9e-4/side; 2.6x headroom
constexpr int PAIR_CAP = 1 << 19; // 512K pairs (expected ~40-80K)

typedef _Float16 half8 __attribute__((ext_vector_type(8)));
typedef float    f32x4 __attribute__((ext_vector_type(4)));

// ---- bitwise replica of np.sum(x*x,-1) fp32 pairwise (AVX512 npyv tree) ----
__global__ __launch_bounds__(256) void rowsq_kernel(const float* __restrict__ x,
                                                    float* __restrict__ out) {
  int row  = (blockIdx.x * 256 + threadIdx.x) >> 6;  // one row per wave
  int lane = threadIdx.x & 63;
  int blk = lane >> 4, l16 = lane & 15;
  const float* p = x + (size_t)row * DIMS + blk * 128 + l16;
  float A[8];
  #pragma unroll
  for (int j = 0; j < 8; ++j) { float v = p[16 * j]; A[j] = __fmul_rn(v, v); }
  float u = __fadd_rn(__fadd_rn(__fadd_rn(A[0], A[1]), __fadd_rn(A[2], A[3])),
                      __fadd_rn(__fadd_rn(A[4], A[5]), __fadd_rn(A[6], A[7])));
  u = __fadd_rn(u, __shfl_xor(u, 8, 64));
  u = __fadd_rn(u, __shfl_xor(u, 4, 64));
  u = __fadd_rn(u, __shfl_xor(u, 2, 64));
  u = __fadd_rn(u, __shfl_xor(u, 1, 64));
  u = __fadd_rn(u, __shfl_xor(u, 16, 64));
  u = __fadd_rn(u, __shfl_xor(u, 32, 64));
  if (lane == 0) out[row] = u;
}

// ---- fp32 -> fp16 converters (codebook scaled by 2^11, exact pow2) ----
__global__ __launch_bounds__(256) void cvt_cb_kernel(const float* __restrict__ cb,
                                                     _Float16* __restrict__ chs) {
  int i = blockIdx.x * 256 + threadIdx.x;          // 4 elements per thread
  float4 v = ((const float4*)cb)[i];
  union { _Float16 h[4]; uint2 u; } p;
  p.h[0] = (_Float16)(v.x * 2048.0f);
  p.h[1] = (_Float16)(v.y * 2048.0f);
  p.h[2] = (_Float16)(v.z * 2048.0f);
  p.h[3] = (_Float16)(v.w * 2048.0f);
  ((uint2*)chs)[i] = p.u;
}
__global__ __launch_bounds__(256) void cvt_z_kernel(const float* __restrict__ z,
                                                    _Float16* __restrict__ zh) {
  int i = blockIdx.x * 256 + threadIdx.x;
  float4 v = ((const float4*)z)[i];
  union { _Float16 h[4]; uint2 u; } p;
  p.h[0] = (_Float16)v.x; p.h[1] = (_Float16)v.y;
  p.h[2] = (_Float16)v.z; p.h[3] = (_Float16)v.w;
  ((uint2*)zh)[i] = p.u;
}

// ---- Phase 1: 128x128 MFMA tiles, tile-min reduce + candidate append ----
constexpr int LDH = 72;  // fp16 row stride (64 + 8 pad -> 2-way banks, free)
template <bool ZH>
__global__ __launch_bounds__(256, 2) void vq_mfma_kernel(
    const float* __restrict__ z, const _Float16* __restrict__ zh,
    const _Float16* __restrict__ chs,
    const float* __restrict__ csq, const float* __restrict__ zsq,
    int* __restrict__ cand_g, int* __restrict__ cnt_g) {
  __shared__ __align__(16) _Float16 Ah[128 * LDH];
  __shared__ __align__(16) _Float16 Bh[128 * LDH];
  __shared__ unsigned rowmin_u[128];   // positive floats: uint order == float
  __shared__ int cnt[128];
  __shared__ int cand[128 * CAND];

  const int tid  = threadIdx.x;
  const int half = blockIdx.x & 1;
  const int m0   = (blockIdx.x >> 1) * 128;
  const int nt0  = half * (KCODES / 2);
  const int wave = tid >> 6, lane = tid & 63;
  const int wm = wave >> 1, wn = wave & 1;     // 2x2 wave grid of 64x64
  const int q = lane >> 4, r = lane & 15;

  if (tid < 128) { rowmin_u[tid] = 0x7f800000u; cnt[tid] = 0; }
  __syncthreads();

  float zs[4][4];
  #pragma unroll
  for (int mf = 0; mf < 4; ++mf)
    #pragma unroll
    for (int reg = 0; reg < 4; ++reg)
      zs[mf][reg] = zsq[m0 + wm * 64 + mf * 16 + q * 4 + reg];

  const int rowS = tid >> 1, ksg = (tid & 1) * 32;   // staging map

  for (int t = 0; t < KCODES / 2 / 128; ++t) {
    const int nt = nt0 + t * 128;
    f32x4 acc[4][4];
    #pragma unroll
    for (int mf = 0; mf < 4; ++mf)
      #pragma unroll
      for (int nf = 0; nf < 4; ++nf) acc[mf][nf] = (f32x4){0.f, 0.f, 0.f, 0.f};

    for (int kc = 0; kc < DIMS / 64; ++kc) {
      const int k0 = kc * 64;
      if (ZH) {  // pre-converted fp16 z: straight 64B copy
        const uint4* as = (const uint4*)(zh + (size_t)(m0 + rowS) * DIMS + k0 + ksg);
        uint4* ad = (uint4*)&Ah[rowS * LDH + ksg];
        #pragma unroll
        for (int i = 0; i < 4; ++i) ad[i] = as[i];
      } else {   // convert on the fly
        const float4* src = (const float4*)(z + (size_t)(m0 + rowS) * DIMS + k0 + ksg);
        _Float16* dst = &Ah[rowS * LDH + ksg];
        #pragma unroll
        for (int i = 0; i < 8; ++i) {
          float4 v = src[i];
          union { _Float16 h[4]; uint2 u; } p;
          p.h[0] = (_Float16)v.x; p.h[1] = (_Float16)v.y;
          p.h[2] = (_Float16)v.z; p.h[3] = (_Float16)v.w;
          *(uint2*)(dst + i * 4) = p.u;
        }
      }
      {
        const uint4* bs = (const uint4*)(chs + (size_t)(nt + rowS) * DIMS + k0 + ksg);
        uint4* bd = (uint4*)&Bh[rowS * LDH + ksg];
        #pragma unroll
        for (int i = 0; i < 4; ++i) bd[i] = bs[i];
      }
      __syncthreads();
      #pragma unroll
      for (int ks = 0; ks < 2; ++ks) {
        half8 af[4], bf[4];
        #pragma unroll
        for (int mf = 0; mf < 4; ++mf)
          af[mf] = *(const half8*)&Ah[(wm * 64 + mf * 16 + r) * LDH + ks * 32 + q * 8];
        #pragma unroll
        for (int nf = 0; nf < 4; ++nf)
          bf[nf] = *(const half8*)&Bh[(wn * 64 + nf * 16 + r) * LDH + ks * 32 + q * 8];
        #pragma unroll
        for (int mf = 0; mf < 4; ++mf)
          #pragma unroll
          for (int nf = 0; nf < 4; ++nf)
            acc[mf][nf] = __builtin_amdgcn_mfma_f32_16x16x32_f16(
                af[mf], bf[nf], acc[mf][nf], 0, 0, 0);
      }
      __syncthreads();
    }

    // ---- epilogue: q' = fl(fl(zsq - acc*2^-10) + csq); C/D row=q*4+reg col=r
    float cs[4];
    #pragma unroll
    for (int nf = 0; nf < 4; ++nf) cs[nf] = csq[nt + wn * 64 + nf * 16 + r];
    float sv[4][4][4];   // [mf][nf][reg]
    float m4[4][4];      // [mf][reg] lane-local min over nf
    #pragma unroll
    for (int mf = 0; mf < 4; ++mf)
      #pragma unroll
      for (int reg = 0; reg < 4; ++reg) {
        float mn = INFINITY;
        #pragma unroll
        for (int nf = 0; nf < 4; ++nf) {
          float s = __fadd_rn(__fmaf_rn(-0.0009765625f, acc[mf][nf][reg],
                                        zs[mf][reg]), cs[nf]);
          sv[mf][nf][reg] = s;
          mn = fminf(mn, s);
        }
        m4[mf][reg] = mn;
      }
    // wave-level row-min across the 16 lanes (r) sharing each row
    #pragma unroll
    for (int mf = 0; mf < 4; ++mf)
      #pragma unroll
      for (int reg = 0; reg < 4; ++reg) {
        float v = m4[mf][reg];
        v = fminf(v, __shfl_xor(v, 1, 64));
        v = fminf(v, __shfl_xor(v, 2, 64));
        v = fminf(v, __shfl_xor(v, 4, 64));
        v = fminf(v, __shfl_xor(v, 8, 64));
        m4[mf][reg] = v;
      }
    if (r == 0) {
      #pragma unroll
      for (int mf = 0; mf < 4; ++mf)
        #pragma unroll
        for (int reg = 0; reg < 4; ++reg)
          atomicMin(&rowmin_u[wm * 64 + mf * 16 + q * 4 + reg],
                    __float_as_uint(m4[mf][reg]));
    }
    __syncthreads();   // tile-min now includes this tile, for ALL rows
    #pragma unroll
    for (int mf = 0; mf < 4; ++mf)
      #pragma unroll
      for (int reg = 0; reg < 4; ++reg) {
        const int row = wm * 64 + mf * 16 + q * 4 + reg;
        float thr = __uint_as_float(rowmin_u[row]) + MARGIN;
        #pragma unroll
        for (int nf = 0; nf < 4; ++nf)
          if (sv[mf][nf][reg] <= thr) {
            int slot = atomicAdd(&cnt[row], 1);
            if (slot < CAND)
              cand[row * CAND + slot] = nt + wn * 64 + nf * 16 + r;
          }
      }
    // next tile's atomicMin is separated from this append by the kc-loop
    // barriers, so no extra __syncthreads needed here.
  }
  __syncthreads();
  if (tid < 128) cnt_g[(size_t)half * N_ROWS + m0 + tid] = cnt[tid];
  for (int i = tid; i < 128 * CAND; i += 256)
    cand_g[((size_t)half * N_ROWS + m0 + i / CAND) * CAND + (i % CAND)] = cand[i];
}

// ---- exact bitwise-np score (R2-verified): dual-panel seq FMA chain ----
__device__ __forceinline__ float exact_q(const float* zr, const float* cr,
                                         float zsr, float csr) {
  float s1 = 0.f;
  for (int k = 0; k < 384; k += 8) {
    float4 a0 = *(const float4*)(zr + k), a1 = *(const float4*)(zr + k + 4);
    float4 b0 = *(const float4*)(cr + k), b1 = *(const float4*)(cr + k + 4);
    s1 = __fmaf_rn(a0.x, b0.x, s1); s1 = __fmaf_rn(a0.y, b0.y, s1);
    s1 = __fmaf_rn(a0.z, b0.z, s1); s1 = __fmaf_rn(a0.w, b0.w, s1);
    s1 = __fmaf_rn(a1.x, b1.x, s1); s1 = __fmaf_rn(a1.y, b1.y, s1);
    s1 = __fmaf_rn(a1.z, b1.z, s1); s1 = __fmaf_rn(a1.w, b1.w, s1);
  }
  float s2 = 0.f;
  for (int k = 384; k < 512; k += 8) {
    float4 a0 = *(const float4*)(zr + k), a1 = *(const float4*)(zr + k + 4);
    float4 b0 = *(const float4*)(cr + k), b1 = *(const float4*)(cr + k + 4);
    s2 = __fmaf_rn(a0.x, b0.x, s2); s2 = __fmaf_rn(a0.y, b0.y, s2);
    s2 = __fmaf_rn(a0.z, b0.z, s2); s2 = __fmaf_rn(a0.w, b0.w, s2);
    s2 = __fmaf_rn(a1.x, b1.x, s2); s2 = __fmaf_rn(a1.y, b1.y, s2);
    s2 = __fmaf_rn(a1.z, b1.z, s2); s2 = __fmaf_rn(a1.w, b1.w, s2);
  }
  float cross = __fadd_rn(s1, s2);                 // fl(S1 + S2)
  return __fadd_rn(__fmaf_rn(-2.f, cross, zsr), csr);
}

// ---- Phase 2a: triage rows. tot==1 -> decided (margin-sound superset);
//      tot>=2 -> append dense (row,code) pairs; overflow -> fallback list.
__global__ __launch_bounds__(256) void select_kernel(
    const int* __restrict__ cnt_g, const int* __restrict__ cand_g,
    unsigned long long* __restrict__ best, unsigned* __restrict__ pairs,
    int* __restrict__ meta, int* __restrict__ ovf) {
  const int row  = blockIdx.x * 256 + threadIdx.x;
  const int lane = threadIdx.x & 63;
  const int c0 = cnt_g[row], c1 = cnt_g[N_ROWS + row];
  const bool over = (c0 > CAND) || (c1 > CAND) || (c0 + c1 == 0);
  const int tot = over ? 0 : c0 + c1;
  unsigned long long bkey = ~0ULL;
  int need = 0;
  if (tot == 1) {
    // Singleton candidate set: it provably contains the exact argmin, and an
    // exact tie would have forced both codes into the set -> this IS argmin.
    int code = (c0 == 1) ? cand_g[(size_t)row * CAND]
                         : cand_g[(size_t)(N_ROWS + row) * CAND];
    bkey = (unsigned long long)(unsigned)code;   // key low32 = code
  } else if (tot >= 2) {
    need = tot;
  }
  best[row] = bkey;                               // init for atomicMin / final
  // wave-aggregated worklist allocation (1 atomic per wave)
  int pre = need;
  #pragma unroll
  for (int off = 1; off < 64; off <<= 1) {
    int v = __shfl_up(pre, off, 64);
    if (lane >= off) pre += v;
  }
  int wtot = __shfl(pre, 63, 64);
  int base = 0;
  if (lane == 63 && wtot > 0) base = atomicAdd(&meta[0], wtot);
  base = __shfl(base, 63, 64);
  const int my0 = base + pre - need;              // exclusive prefix
  bool row_ovf = over;
  if (need > 0) {
    int nfit = PAIR_CAP - my0;                    // may be <= 0
    if (nfit < need) row_ovf = true;              // fallback overwrites best
    int nw = need < nfit ? need : nfit;
    for (int j = 0; j < nw; ++j) {
      int code = (j < c0) ? cand_g[(size_t)row * CAND + j]
                          : cand_g[(size_t)(N_ROWS + row) * CAND + (j - c0)];
      pairs[my0 + j] = ((unsigned)row << 13) | (unsigned)code;
    }
  }
  if (row_ovf) { int s = atomicAdd(&meta[1], 1); ovf[s] = row; }
}

// ---- Phase 2b: dense exact rescore, one lane per (row,code) pair.
//      d2 > 0 always (zsq ~ 512) so uint order == float order; packed key
//      (q_bits<<32)|code -> atomicMin = argmin with lowest-index tie-break.
__global__ __launch_bounds__(256) void pairs_kernel(
    const float* __restrict__ z, const float* __restrict__ cb,
    const float* __restrict__ zsq, const float* __restrict__ csq,
    const unsigned* __restrict__ pairs, const int* __restrict__ meta,
    unsigned long long* __restrict__ best) {
  int n = meta[0];
  if (n > PAIR_CAP) n = PAIR_CAP;
  const int i = blockIdx.x * 256 + threadIdx.x;
  if (i >= n) return;
  const unsigned p = pairs[i];
  const int row = (int)(p >> 13), code = (int)(p & 8191u);
  const float qv = exact_q(z + (size_t)row * DIMS, cb + (size_t)code * DIMS,
                           zsq[row], csq[code]);
  const unsigned long long key =
      ((unsigned long long)__float_as_uint(qv) << 32) | (unsigned)code;
  atomicMin(&best[row], key);
}

// ---- Phase 2c: full exact scan for overflow rows (correctness net) ----
__global__ __launch_bounds__(256) void fallback_kernel(
    const float* __restrict__ z, const float* __restrict__ cb,
    const float* __restrict__ zsq, const float* __restrict__ csq,
    const int* __restrict__ ovf, const int* __restrict__ meta,
    unsigned long long* __restrict__ best) {
  const int n = meta[1];
  const int wave = (blockIdx.x * 256 + threadIdx.x) >> 6;
  const int lane = threadIdx.x & 63;
  const int nw = (gridDim.x * 256) >> 6;
  for (int wi = wave; wi < n; wi += nw) {
    const int row = ovf[wi];
    const float zsr = zsq[row];
    const float* zr = z + (size_t)row * DIMS;
    float bq = INFINITY; int bc = 0x7fffffff;
    for (int base = 0; base < KCODES; base += 64) {
      int code = base + lane;
      float qv = exact_q(zr, cb + (size_t)code * DIMS, zsr, csq[code]);
      if (qv < bq || (qv == bq && code < bc)) { bq = qv; bc = code; }
    }
    #pragma unroll
    for (int off = 32; off > 0; off >>= 1) {
      float q2 = __shfl_xor(bq, off, 64);
      int   c2 = __shfl_xor(bc, off, 64);
      if (q2 < bq || (q2 == bq && c2 < bc)) { bq = q2; bc = c2; }
    }
    if (lane == 0)
      best[row] = ((unsigned long long)__float_as_uint(bq) << 32) | (unsigned)bc;
  }
}

// ---- Phase 2d: coalesced gather of winner rows + index write ----
__global__ __launch_bounds__(256) void gather_kernel(
    const float* __restrict__ cb, const unsigned long long* __restrict__ best,
    float* __restrict__ zq, float* __restrict__ idx_out) {
  const int wave = threadIdx.x >> 6, lane = threadIdx.x & 63;
  const int row = blockIdx.x * 4 + wave;
  const int code = (int)(unsigned)(best[row] & 0xFFFFFFFFu);
  if (lane == 0) idx_out[row] = (float)code;
  const float4* cbv = (const float4*)(cb + (size_t)code * DIMS);
  float4* zqv = (float4*)(zq + (size_t)row * DIMS);
  zqv[lane]      = cbv[lane];
  zqv[lane + 64] = cbv[lane + 64];
}

extern "C" void kernel_launch(void* const* d_in, const int* in_sizes, int n_in,
                              void* d_out, int out_size, void* d_ws, size_t ws_size,
                              hipStream_t stream) {
  const float* z  = (const float*)d_in[0];
  const float* cb = (const float*)d_in[1];
  float* out     = (float*)d_out;
  float* zq      = out;
  float* idx_out = out + (size_t)N_ROWS * DIMS;

  // workspace layout (all chunks 256B-multiples)
  char* w = (char*)d_ws;
  _Float16* cbh = (_Float16*)w;            w += (size_t)KCODES * DIMS * 2;   // 8 MB
  float* zsq = (float*)w;                  w += (size_t)N_ROWS * 4;          // 128 KB
  float* csq = (float*)w;                  w += (size_t)KCODES * 4;          // 32 KB
  int* cnt_g = (int*)w;                    w += (size_t)2 * N_ROWS * 4;      // 256 KB
  int* cand_g = (int*)w;                   w += (size_t)2 * N_ROWS * CAND * 4; // 8 MB
  unsigned long long* best = (unsigned long long*)w; w += (size_t)N_ROWS * 8;  // 256 KB
  unsigned* pairs = (unsigned*)w;          w += (size_t)PAIR_CAP * 4;        // 2 MB
  int* meta = (int*)w;                     w += 256;                         // counters
  int* ovf = (int*)w;                      w += (size_t)N_ROWS * 4;          // 128 KB
  _Float16* zh = (_Float16*)w;             w += (size_t)N_ROWS * DIMS * 2;   // 32 MB
  bool use_zh = ((size_t)(w - (char*)d_ws) <= ws_size);

  hipMemsetAsync(meta, 0, 256, stream);

  rowsq_kernel<<<N_ROWS / 4, 256, 0, stream>>>(z, zsq);
  rowsq_kernel<<<KCODES / 4, 256, 0, stream>>>(cb, csq);
  cvt_cb_kernel<<<KCODES * DIMS / 1024, 256, 0, stream>>>(cb, cbh);
  if (use_zh) {
    cvt_z_kernel<<<N_ROWS * DIMS / 1024, 256, 0, stream>>>(z, zh);
    vq_mfma_kernel<true><<<(N_ROWS / 128) * 2, 256, 0, stream>>>(
        z, zh, cbh, csq, zsq, cand_g, cnt_g);
  } else {
    vq_mfma_kernel<false><<<(N_ROWS / 128) * 2, 256, 0, stream>>>(
        z, nullptr, cbh, csq, zsq, cand_g, cnt_g);
  }
  select_kernel<<<N_ROWS / 256, 256, 0, stream>>>(cnt_g, cand_g, best, pairs,
                                                  meta, ovf);
  pairs_kernel<<<PAIR_CAP / 256, 256, 0, stream>>>(z, cb, zsq, csq, pairs,
                                                   meta, best);
  fallback_kernel<<<64, 256, 0, stream>>>(z, cb, zsq, csq, ovf, meta, best);
  gather_kernel<<<N_ROWS / 4, 256, 0, stream>>>(cb, best, zq, idx_out);
}

// Round 2
// 2990.011 us; speedup vs baseline: 23.4550x; 23.4550x over previous
//
#include <hip/hip_runtime.h>
#include <cstdint>
#include <cstddef>

// VQ nearest-codebook, two-phase:
//   P1: fp16 MFMA approx scores -> per-row candidate set (superset, margin-sound).
//       R2 fix: candidates stored WITH fp16 approx-delta score; a final-min
//       filter pass inside the kernel removes running-min-inflated entries
//       (R1 root cause: ~5-15 stale candidates/row overflowed the pair cap ->
//        thousands of rows hit the serial fallback -> 66 ms).
//   P2: select (cross-half merge + singleton decide) -> dense pair worklist
//       -> packed u64 atomicMin argmin -> throughput fallback net -> gather.
constexpr int N_ROWS = 32768;
constexpr int KCODES = 8192;
constexpr int DIMS   = 512;
constexpr int CAND   = 32;
constexpr float MARGIN = 1e-3f;   // approx err ~2e-4/side incl fp16 store slop
constexpr int PAIR_CAP = 1 << 18; // 256K pairs (post-filter expectation ~75K)
constexpr unsigned SENT = 0xFFFFFFFFu;

typedef _Float16 half8 __attribute__((ext_vector_type(8)));
typedef float    f32x4 __attribute__((ext_vector_type(4)));

// packed candidate: high16 = fp16 bits of delta (= csq - 2*z.c approx),
// low16 = 13-bit global code id. Delta compares equal-offset per row (zsq).
__device__ __forceinline__ unsigned pack_ds(float d, int code) {
  union { _Float16 h; unsigned short u; } c; c.h = (_Float16)d;
  return ((unsigned)c.u << 16) | (unsigned)code;
}
__device__ __forceinline__ float unpack_d(unsigned e) {
  union { _Float16 h; unsigned short u; } c; c.u = (unsigned short)(e >> 16);
  return (float)c.h;
}

// ---- bitwise replica of np.sum(x*x,-1) fp32 pairwise (AVX512 npyv tree) ----
__global__ __launch_bounds__(256) void rowsq_kernel(const float* __restrict__ x,
                                                    float* __restrict__ out) {
  int row  = (blockIdx.x * 256 + threadIdx.x) >> 6;  // one row per wave
  int lane = threadIdx.x & 63;
  int blk = lane >> 4, l16 = lane & 15;
  const float* p = x + (size_t)row * DIMS + blk * 128 + l16;
  float A[8];
  #pragma unroll
  for (int j = 0; j < 8; ++j) { float v = p[16 * j]; A[j] = __fmul_rn(v, v); }
  float u = __fadd_rn(__fadd_rn(__fadd_rn(A[0], A[1]), __fadd_rn(A[2], A[3])),
                      __fadd_rn(__fadd_rn(A[4], A[5]), __fadd_rn(A[6], A[7])));
  u = __fadd_rn(u, __shfl_xor(u, 8, 64));
  u = __fadd_rn(u, __shfl_xor(u, 4, 64));
  u = __fadd_rn(u, __shfl_xor(u, 2, 64));
  u = __fadd_rn(u, __shfl_xor(u, 1, 64));
  u = __fadd_rn(u, __shfl_xor(u, 16, 64));
  u = __fadd_rn(u, __shfl_xor(u, 32, 64));
  if (lane == 0) out[row] = u;
}

// ---- fp32 -> fp16 converters (codebook scaled by 2^11, exact pow2) ----
__global__ __launch_bounds__(256) void cvt_cb_kernel(const float* __restrict__ cb,
                                                     _Float16* __restrict__ chs) {
  int i = blockIdx.x * 256 + threadIdx.x;          // 4 elements per thread
  float4 v = ((const float4*)cb)[i];
  union { _Float16 h[4]; uint2 u; } p;
  p.h[0] = (_Float16)(v.x * 2048.0f);
  p.h[1] = (_Float16)(v.y * 2048.0f);
  p.h[2] = (_Float16)(v.z * 2048.0f);
  p.h[3] = (_Float16)(v.w * 2048.0f);
  ((uint2*)chs)[i] = p.u;
}
__global__ __launch_bounds__(256) void cvt_z_kernel(const float* __restrict__ z,
                                                    _Float16* __restrict__ zh) {
  int i = blockIdx.x * 256 + threadIdx.x;
  float4 v = ((const float4*)z)[i];
  union { _Float16 h[4]; uint2 u; } p;
  p.h[0] = (_Float16)v.x; p.h[1] = (_Float16)v.y;
  p.h[2] = (_Float16)v.z; p.h[3] = (_Float16)v.w;
  ((uint2*)zh)[i] = p.u;
}

// ---- Phase 1: 128x128 MFMA tiles; delta-score min + filtered candidates ----
constexpr int LDH = 72;  // fp16 row stride (64 + 8 pad -> 2-way banks, free)
template <bool ZH>
__global__ __launch_bounds__(256, 2) void vq_mfma_kernel(
    const float* __restrict__ z, const _Float16* __restrict__ zh,
    const _Float16* __restrict__ chs, const float* __restrict__ csq,
    unsigned* __restrict__ cand_g, int* __restrict__ cnt_g) {
  __shared__ __align__(16) _Float16 Ah[128 * LDH];
  __shared__ __align__(16) _Float16 Bh[128 * LDH];
  __shared__ unsigned rowmin_u[128];   // key = float_as_uint(delta + 4.0f) > 0
  __shared__ int cnt[128];
  __shared__ unsigned cand[128 * CAND];

  const int tid  = threadIdx.x;
  const int half = blockIdx.x & 1;
  const int m0   = (blockIdx.x >> 1) * 128;
  const int nt0  = half * (KCODES / 2);
  const int wave = tid >> 6, lane = tid & 63;
  const int wm = wave >> 1, wn = wave & 1;     // 2x2 wave grid of 64x64
  const int q = lane >> 4, r = lane & 15;

  if (tid < 128) { rowmin_u[tid] = 0x7f800000u; cnt[tid] = 0; }
  __syncthreads();

  const int rowS = tid >> 1, ksg = (tid & 1) * 32;   // staging map

  for (int t = 0; t < KCODES / 2 / 128; ++t) {
    const int nt = nt0 + t * 128;
    f32x4 acc[4][4];
    #pragma unroll
    for (int mf = 0; mf < 4; ++mf)
      #pragma unroll
      for (int nf = 0; nf < 4; ++nf) acc[mf][nf] = (f32x4){0.f, 0.f, 0.f, 0.f};

    for (int kc = 0; kc < DIMS / 64; ++kc) {
      const int k0 = kc * 64;
      if (ZH) {  // pre-converted fp16 z: straight 64B copy
        const uint4* as = (const uint4*)(zh + (size_t)(m0 + rowS) * DIMS + k0 + ksg);
        uint4* ad = (uint4*)&Ah[rowS * LDH + ksg];
        #pragma unroll
        for (int i = 0; i < 4; ++i) ad[i] = as[i];
      } else {   // convert on the fly
        const float4* src = (const float4*)(z + (size_t)(m0 + rowS) * DIMS + k0 + ksg);
        _Float16* dst = &Ah[rowS * LDH + ksg];
        #pragma unroll
        for (int i = 0; i < 8; ++i) {
          float4 v = src[i];
          union { _Float16 h[4]; uint2 u; } p;
          p.h[0] = (_Float16)v.x; p.h[1] = (_Float16)v.y;
          p.h[2] = (_Float16)v.z; p.h[3] = (_Float16)v.w;
          *(uint2*)(dst + i * 4) = p.u;
        }
      }
      {
        const uint4* bs = (const uint4*)(chs + (size_t)(nt + rowS) * DIMS + k0 + ksg);
        uint4* bd = (uint4*)&Bh[rowS * LDH + ksg];
        #pragma unroll
        for (int i = 0; i < 4; ++i) bd[i] = bs[i];
      }
      __syncthreads();
      #pragma unroll
      for (int ks = 0; ks < 2; ++ks) {
        half8 af[4], bf[4];
        #pragma unroll
        for (int mf = 0; mf < 4; ++mf)
          af[mf] = *(const half8*)&Ah[(wm * 64 + mf * 16 + r) * LDH + ks * 32 + q * 8];
        #pragma unroll
        for (int nf = 0; nf < 4; ++nf)
          bf[nf] = *(const half8*)&Bh[(wn * 64 + nf * 16 + r) * LDH + ks * 32 + q * 8];
        #pragma unroll
        for (int mf = 0; mf < 4; ++mf)
          #pragma unroll
          for (int nf = 0; nf < 4; ++nf)
            acc[mf][nf] = __builtin_amdgcn_mfma_f32_16x16x32_f16(
                af[mf], bf[nf], acc[mf][nf], 0, 0, 0);
      }
      __syncthreads();
    }

    // ---- epilogue on delta = fl(csq - acc*2^-10)  (== sv - zsq, tiny mag,
    //      so fp32 rounding ~1e-8 and fp16 storage ~3e-5 -- margin-safe).
    //      C/D layout: row=q*4+reg, col=r.
    float cs[4];
    #pragma unroll
    for (int nf = 0; nf < 4; ++nf) cs[nf] = csq[nt + wn * 64 + nf * 16 + r];
    float m4[4][4];      // [mf][reg] lane-local min over nf
    #pragma unroll
    for (int mf = 0; mf < 4; ++mf)
      #pragma unroll
      for (int reg = 0; reg < 4; ++reg) {
        float mn = INFINITY;
        #pragma unroll
        for (int nf = 0; nf < 4; ++nf)
          mn = fminf(mn, __fmaf_rn(-0.0009765625f, acc[mf][nf][reg], cs[nf]));
        m4[mf][reg] = mn;
      }
    #pragma unroll
    for (int mf = 0; mf < 4; ++mf)
      #pragma unroll
      for (int reg = 0; reg < 4; ++reg) {
        float v = m4[mf][reg];
        v = fminf(v, __shfl_xor(v, 1, 64));
        v = fminf(v, __shfl_xor(v, 2, 64));
        v = fminf(v, __shfl_xor(v, 4, 64));
        v = fminf(v, __shfl_xor(v, 8, 64));
        m4[mf][reg] = v;
      }
    if (r == 0) {
      #pragma unroll
      for (int mf = 0; mf < 4; ++mf)
        #pragma unroll
        for (int reg = 0; reg < 4; ++reg)
          atomicMin(&rowmin_u[wm * 64 + mf * 16 + q * 4 + reg],
                    __float_as_uint(m4[mf][reg] + 4.0f));  // delta+4 > 0 always
    }
    __syncthreads();   // tile-min now includes this tile, for ALL rows
    #pragma unroll
    for (int mf = 0; mf < 4; ++mf)
      #pragma unroll
      for (int reg = 0; reg < 4; ++reg) {
        const int row = wm * 64 + mf * 16 + q * 4 + reg;
        float thr = __uint_as_float(rowmin_u[row]) - 4.0f + MARGIN;
        #pragma unroll
        for (int nf = 0; nf < 4; ++nf) {
          float d = __fmaf_rn(-0.0009765625f, acc[mf][nf][reg], cs[nf]);
          if (d <= thr) {
            int slot = atomicAdd(&cnt[row], 1);
            if (slot < CAND)
              cand[row * CAND + slot] = pack_ds(d, nt + wn * 64 + nf * 16 + r);
          }
        }
      }
    // next tile's atomicMin is separated from this append by the kc-loop
    // barriers, so no extra __syncthreads needed here.
  }
  __syncthreads();
  // ---- final-min filter: drop running-min-inflated entries (R1 root cause)
  if (tid < 128) {
    const int row = tid;
    const int raw = cnt[row];
    const int m = raw < CAND ? raw : CAND;
    const float thr = __uint_as_float(rowmin_u[row]) - 4.0f + MARGIN;
    int k = 0;
    for (int i = 0; i < m; ++i) {
      unsigned e = cand[row * CAND + i];
      if (unpack_d(e) <= thr) cand[row * CAND + k++] = e;  // in-place compact
    }
    cnt[row] = (raw > CAND) ? raw : k;   // raw>CAND -> overflow marker kept
  }
  __syncthreads();
  if (tid < 128) cnt_g[(size_t)half * N_ROWS + m0 + tid] = cnt[tid];
  for (int i = tid; i < 128 * CAND; i += 256)
    cand_g[((size_t)half * N_ROWS + m0 + i / CAND) * CAND + (i % CAND)] = cand[i];
}

// ---- exact bitwise-np score (R2-verified): dual-panel seq FMA chain ----
__device__ __forceinline__ float exact_q(const float* zr, const float* cr,
                                         float zsr, float csr) {
  float s1 = 0.f;
  for (int k = 0; k < 384; k += 8) {
    float4 a0 = *(const float4*)(zr + k), a1 = *(const float4*)(zr + k + 4);
    float4 b0 = *(const float4*)(cr + k), b1 = *(const float4*)(cr + k + 4);
    s1 = __fmaf_rn(a0.x, b0.x, s1); s1 = __fmaf_rn(a0.y, b0.y, s1);
    s1 = __fmaf_rn(a0.z, b0.z, s1); s1 = __fmaf_rn(a0.w, b0.w, s1);
    s1 = __fmaf_rn(a1.x, b1.x, s1); s1 = __fmaf_rn(a1.y, b1.y, s1);
    s1 = __fmaf_rn(a1.z, b1.z, s1); s1 = __fmaf_rn(a1.w, b1.w, s1);
  }
  float s2 = 0.f;
  for (int k = 384; k < 512; k += 8) {
    float4 a0 = *(const float4*)(zr + k), a1 = *(const float4*)(zr + k + 4);
    float4 b0 = *(const float4*)(cr + k), b1 = *(const float4*)(cr + k + 4);
    s2 = __fmaf_rn(a0.x, b0.x, s2); s2 = __fmaf_rn(a0.y, b0.y, s2);
    s2 = __fmaf_rn(a0.z, b0.z, s2); s2 = __fmaf_rn(a0.w, b0.w, s2);
    s2 = __fmaf_rn(a1.x, b1.x, s2); s2 = __fmaf_rn(a1.y, b1.y, s2);
    s2 = __fmaf_rn(a1.z, b1.z, s2); s2 = __fmaf_rn(a1.w, b1.w, s2);
  }
  float cross = __fadd_rn(s1, s2);                 // fl(S1 + S2)
  return __fadd_rn(__fmaf_rn(-2.f, cross, zsr), csr);
}

// ---- Phase 2a: cross-half merge. Global approx-min filter; singleton rows
//      decided free (competitors provably > margin away); rest -> pair list.
__global__ __launch_bounds__(256) void select_kernel(
    const int* __restrict__ cnt_g, const unsigned* __restrict__ cand_g,
    unsigned long long* __restrict__ best, unsigned* __restrict__ pairs,
    int* __restrict__ meta, int* __restrict__ ovf) {
  const int row  = blockIdx.x * 256 + threadIdx.x;
  const int lane = threadIdx.x & 63;
  const int c0 = cnt_g[row], c1 = cnt_g[N_ROWS + row];
  const bool over = (c0 > CAND) || (c1 > CAND) || (c0 + c1 == 0);
  unsigned long long bkey = ~0ULL;
  int need = 0;
  float thr = 0.f;
  if (!over) {
    float gm = INFINITY;
    for (int j = 0; j < c0; ++j)
      gm = fminf(gm, unpack_d(cand_g[(size_t)row * CAND + j]));
    for (int j = 0; j < c1; ++j)
      gm = fminf(gm, unpack_d(cand_g[(size_t)(N_ROWS + row) * CAND + j]));
    thr = gm + MARGIN;
    int k = 0; unsigned first = 0;
    for (int j = 0; j < c0; ++j) {
      unsigned e = cand_g[(size_t)row * CAND + j];
      if (unpack_d(e) <= thr) { if (k == 0) first = e; ++k; }
    }
    for (int j = 0; j < c1; ++j) {
      unsigned e = cand_g[(size_t)(N_ROWS + row) * CAND + j];
      if (unpack_d(e) <= thr) { if (k == 0) first = e; ++k; }
    }
    if (k == 1) bkey = (unsigned long long)(first & 0x1FFFu);  // decided
    else need = k;
  }
  best[row] = bkey;
  // wave-aggregated worklist allocation (1 atomic per wave)
  int pre = need;
  #pragma unroll
  for (int off = 1; off < 64; off <<= 1) {
    int v = __shfl_up(pre, off, 64);
    if (lane >= off) pre += v;
  }
  int wtot = __shfl(pre, 63, 64);
  int base = 0;
  if (lane == 63 && wtot > 0) base = atomicAdd(&meta[0], wtot);
  base = __shfl(base, 63, 64);
  const int my0 = base + pre - need;              // exclusive prefix
  bool row_ovf = over;
  if (need > 0) {
    if (my0 + need > PAIR_CAP) {
      row_ovf = true;                             // fallback handles this row
      for (int j = 0; j < need; ++j) {            // sentinel allocated slots
        int s = my0 + j;
        if (s < PAIR_CAP) pairs[s] = SENT;
      }
    } else {
      int kk = 0;
      for (int j = 0; j < c0 + c1; ++j) {
        unsigned e = (j < c0) ? cand_g[(size_t)row * CAND + j]
                              : cand_g[(size_t)(N_ROWS + row) * CAND + (j - c0)];
        if (unpack_d(e) <= thr)
          pairs[my0 + kk++] = ((unsigned)row << 13) | (e & 0x1FFFu);
      }
    }
  }
  if (row_ovf) { int s = atomicAdd(&meta[1], 1); ovf[s] = row; }
}

// ---- Phase 2b: dense exact rescore, one lane per (row,code) pair.
//      d2 > 0 always (zsq ~ 512) so uint order == float order; packed key
//      (q_bits<<32)|code -> atomicMin = argmin with lowest-index tie-break.
__global__ __launch_bounds__(256) void pairs_kernel(
    const float* __restrict__ z, const float* __restrict__ cb,
    const float* __restrict__ zsq, const float* __restrict__ csq,
    const unsigned* __restrict__ pairs, const int* __restrict__ meta,
    unsigned long long* __restrict__ best) {
  int n = meta[0];
  if (n > PAIR_CAP) n = PAIR_CAP;
  const int i = blockIdx.x * 256 + threadIdx.x;
  if (i >= n) return;
  const unsigned p = pairs[i];
  if (p == SENT) return;                          // unfilled overflow slot
  const int row = (int)(p >> 13), code = (int)(p & 8191u);
  const float qv = exact_q(z + (size_t)row * DIMS, cb + (size_t)code * DIMS,
                           zsq[row], csq[code]);
  const unsigned long long key =
      ((unsigned long long)__float_as_uint(qv) << 32) | (unsigned)code;
  atomicMin(&best[row], key);
}

// ---- Phase 2c: full exact scan for overflow rows. 8192 waves grid-stride:
//      bounded ~1ms even if EVERY row lands here (R1's 64-block version
//      serialized thousands of rows -> 66 ms).
__global__ __launch_bounds__(256) void fallback_kernel(
    const float* __restrict__ z, const float* __restrict__ cb,
    const float* __restrict__ zsq, const float* __restrict__ csq,
    const int* __restrict__ ovf, const int* __restrict__ meta,
    unsigned long long* __restrict__ best) {
  const int n = meta[1];
  const int wave = (blockIdx.x * 256 + threadIdx.x) >> 6;
  const int lane = threadIdx.x & 63;
  const int nw = (gridDim.x * 256) >> 6;
  for (int wi = wave; wi < n; wi += nw) {
    const int row = ovf[wi];
    const float zsr = zsq[row];
    const float* zr = z + (size_t)row * DIMS;
    float bq = INFINITY; int bc = 0x7fffffff;
    for (int base = 0; base < KCODES; base += 64) {
      int code = base + lane;
      float qv = exact_q(zr, cb + (size_t)code * DIMS, zsr, csq[code]);
      if (qv < bq || (qv == bq && code < bc)) { bq = qv; bc = code; }
    }
    #pragma unroll
    for (int off = 32; off > 0; off >>= 1) {
      float q2 = __shfl_xor(bq, off, 64);
      int   c2 = __shfl_xor(bc, off, 64);
      if (q2 < bq || (q2 == bq && c2 < bc)) { bq = q2; bc = c2; }
    }
    if (lane == 0)
      best[row] = ((unsigned long long)__float_as_uint(bq) << 32) | (unsigned)bc;
  }
}

// ---- Phase 2d: coalesced gather of winner rows + index write ----
__global__ __launch_bounds__(256) void gather_kernel(
    const float* __restrict__ cb, const unsigned long long* __restrict__ best,
    float* __restrict__ zq, float* __restrict__ idx_out) {
  const int wave = threadIdx.x >> 6, lane = threadIdx.x & 63;
  const int row = blockIdx.x * 4 + wave;
  const int code = (int)(unsigned)(best[row] & 0xFFFFFFFFu);
  if (lane == 0) idx_out[row] = (float)code;
  const float4* cbv = (const float4*)(cb + (size_t)code * DIMS);
  float4* zqv = (float4*)(zq + (size_t)row * DIMS);
  zqv[lane]      = cbv[lane];
  zqv[lane + 64] = cbv[lane + 64];
}

extern "C" void kernel_launch(void* const* d_in, const int* in_sizes, int n_in,
                              void* d_out, int out_size, void* d_ws, size_t ws_size,
                              hipStream_t stream) {
  const float* z  = (const float*)d_in[0];
  const float* cb = (const float*)d_in[1];
  float* out     = (float*)d_out;
  float* zq      = out;
  float* idx_out = out + (size_t)N_ROWS * DIMS;

  // workspace layout (all chunks 256B-multiples)
  char* w = (char*)d_ws;
  _Float16* cbh = (_Float16*)w;            w += (size_t)KCODES * DIMS * 2;   // 8 MB
  float* zsq = (float*)w;                  w += (size_t)N_ROWS * 4;          // 128 KB
  float* csq = (float*)w;                  w += (size_t)KCODES * 4;          // 32 KB
  int* cnt_g = (int*)w;                    w += (size_t)2 * N_ROWS * 4;      // 256 KB
  unsigned* cand_g = (unsigned*)w;         w += (size_t)2 * N_ROWS * CAND * 4; // 8 MB
  unsigned long long* best = (unsigned long long*)w; w += (size_t)N_ROWS * 8;  // 256 KB
  unsigned* pairs = (unsigned*)w;          w += (size_t)PAIR_CAP * 4;        // 1 MB
  int* meta = (int*)w;                     w += 256;                         // counters
  int* ovf = (int*)w;                      w += (size_t)N_ROWS * 4;          // 128 KB
  _Float16* zh = (_Float16*)w;             w += (size_t)N_ROWS * DIMS * 2;   // 32 MB
  bool use_zh = ((size_t)(w - (char*)d_ws) <= ws_size);

  hipMemsetAsync(meta, 0, 256, stream);

  rowsq_kernel<<<N_ROWS / 4, 256, 0, stream>>>(z, zsq);
  rowsq_kernel<<<KCODES / 4, 256, 0, stream>>>(cb, csq);
  cvt_cb_kernel<<<KCODES * DIMS / 1024, 256, 0, stream>>>(cb, cbh);
  if (use_zh) {
    cvt_z_kernel<<<N_ROWS * DIMS / 1024, 256, 0, stream>>>(z, zh);
    vq_mfma_kernel<true><<<(N_ROWS / 128) * 2, 256, 0, stream>>>(
        z, zh, cbh, csq, cand_g, cnt_g);
  } else {
    vq_mfma_kernel<false><<<(N_ROWS / 128) * 2, 256, 0, stream>>>(
        z, nullptr, cbh, csq, cand_g, cnt_g);
  }
  select_kernel<<<N_ROWS / 256, 256, 0, stream>>>(cnt_g, cand_g, best, pairs,
                                                  meta, ovf);
  pairs_kernel<<<PAIR_CAP / 256, 256, 0, stream>>>(z, cb, zsq, csq, pairs,
                                                   meta, best);
  fallback_kernel<<<2048, 256, 0, stream>>>(z, cb, zsq, csq, ovf, meta, best);
  gather_kernel<<<N_ROWS / 4, 256, 0, stream>>>(cb, best, zq, idx_out);
}

// Round 3
// 908.615 us; speedup vs baseline: 77.1841x; 3.2907x over previous
//
#include <hip/hip_runtime.h>
#include <cstdint>
#include <cstddef>

// VQ nearest-codebook, two-phase:
//   P1: fp16 MFMA approx scores -> per-row candidate set (superset, margin-sound).
//       R3: periodic LDS compaction vs running min + explicit drop flag
//       (R2 left ~24 rows marked overflow via raw-count inflation).
//   P2: select (cross-half merge + singleton decide) -> dense pair worklist
//       -> packed u64 atomicMin argmin -> gather.
//   Fallback (R3 rewrite): one BLOCK per overflow row, coalesced approx scan
//       (LDS-scored) + exact rescore of codes within a rigorous bound.
//       R2's version was one wave walking 8192 scattered rows = 2.2 ms.
constexpr int N_ROWS = 32768;
constexpr int KCODES = 8192;
constexpr int DIMS   = 512;
constexpr int CAND   = 32;
constexpr float MARGIN = 1e-3f;   // approx err ~2e-4/side incl fp16 store slop
constexpr int PAIR_CAP = 1 << 18; // 256K pairs (post-filter expectation ~75K)
constexpr unsigned SENT = 0xFFFFFFFFu;

typedef _Float16 half8 __attribute__((ext_vector_type(8)));
typedef float    f32x4 __attribute__((ext_vector_type(4)));

// packed candidate: high16 = fp16 bits of delta (= csq - 2*z.c approx),
// low16 = 13-bit global code id. Delta compares equal-offset per row (zsq).
__device__ __forceinline__ unsigned pack_ds(float d, int code) {
  union { _Float16 h; unsigned short u; } c; c.h = (_Float16)d;
  return ((unsigned)c.u << 16) | (unsigned)code;
}
__device__ __forceinline__ float unpack_d(unsigned e) {
  union { _Float16 h; unsigned short u; } c; c.u = (unsigned short)(e >> 16);
  return (float)c.h;
}

// ---- bitwise replica of np.sum(x*x,-1) fp32 pairwise (AVX512 npyv tree) ----
__global__ __launch_bounds__(256) void rowsq_kernel(const float* __restrict__ x,
                                                    float* __restrict__ out) {
  int row  = (blockIdx.x * 256 + threadIdx.x) >> 6;  // one row per wave
  int lane = threadIdx.x & 63;
  int blk = lane >> 4, l16 = lane & 15;
  const float* p = x + (size_t)row * DIMS + blk * 128 + l16;
  float A[8];
  #pragma unroll
  for (int j = 0; j < 8; ++j) { float v = p[16 * j]; A[j] = __fmul_rn(v, v); }
  float u = __fadd_rn(__fadd_rn(__fadd_rn(A[0], A[1]), __fadd_rn(A[2], A[3])),
                      __fadd_rn(__fadd_rn(A[4], A[5]), __fadd_rn(A[6], A[7])));
  u = __fadd_rn(u, __shfl_xor(u, 8, 64));
  u = __fadd_rn(u, __shfl_xor(u, 4, 64));
  u = __fadd_rn(u, __shfl_xor(u, 2, 64));
  u = __fadd_rn(u, __shfl_xor(u, 1, 64));
  u = __fadd_rn(u, __shfl_xor(u, 16, 64));
  u = __fadd_rn(u, __shfl_xor(u, 32, 64));
  if (lane == 0) out[row] = u;
}

// ---- fp32 -> fp16 converters (codebook scaled by 2^11, exact pow2) ----
__global__ __launch_bounds__(256) void cvt_cb_kernel(const float* __restrict__ cb,
                                                     _Float16* __restrict__ chs) {
  int i = blockIdx.x * 256 + threadIdx.x;          // 4 elements per thread
  float4 v = ((const float4*)cb)[i];
  union { _Float16 h[4]; uint2 u; } p;
  p.h[0] = (_Float16)(v.x * 2048.0f);
  p.h[1] = (_Float16)(v.y * 2048.0f);
  p.h[2] = (_Float16)(v.z * 2048.0f);
  p.h[3] = (_Float16)(v.w * 2048.0f);
  ((uint2*)chs)[i] = p.u;
}
__global__ __launch_bounds__(256) void cvt_z_kernel(const float* __restrict__ z,
                                                    _Float16* __restrict__ zh) {
  int i = blockIdx.x * 256 + threadIdx.x;
  float4 v = ((const float4*)z)[i];
  union { _Float16 h[4]; uint2 u; } p;
  p.h[0] = (_Float16)v.x; p.h[1] = (_Float16)v.y;
  p.h[2] = (_Float16)v.z; p.h[3] = (_Float16)v.w;
  ((uint2*)zh)[i] = p.u;
}

// ---- Phase 1: 128x128 MFMA tiles; delta-score min + filtered candidates ----
constexpr int LDH = 72;  // fp16 row stride (64 + 8 pad -> 2-way banks, free)
template <bool ZH>
__global__ __launch_bounds__(256, 2) void vq_mfma_kernel(
    const float* __restrict__ z, const _Float16* __restrict__ zh,
    const _Float16* __restrict__ chs, const float* __restrict__ csq,
    unsigned* __restrict__ cand_g, int* __restrict__ cnt_g) {
  __shared__ __align__(16) _Float16 Ah[128 * LDH];
  __shared__ __align__(16) _Float16 Bh[128 * LDH];
  __shared__ unsigned rowmin_u[128];   // key = float_as_uint(delta + 4.0f) > 0
  __shared__ int cnt[128];
  __shared__ unsigned char dropped[128];
  __shared__ unsigned cand[128 * CAND];

  const int tid  = threadIdx.x;
  const int half = blockIdx.x & 1;
  const int m0   = (blockIdx.x >> 1) * 128;
  const int nt0  = half * (KCODES / 2);
  const int wave = tid >> 6, lane = tid & 63;
  const int wm = wave >> 1, wn = wave & 1;     // 2x2 wave grid of 64x64
  const int q = lane >> 4, r = lane & 15;

  if (tid < 128) { rowmin_u[tid] = 0x7f800000u; cnt[tid] = 0; dropped[tid] = 0; }
  __syncthreads();

  const int rowS = tid >> 1, ksg = (tid & 1) * 32;   // staging map

  for (int t = 0; t < KCODES / 2 / 128; ++t) {
    const int nt = nt0 + t * 128;
    f32x4 acc[4][4];
    #pragma unroll
    for (int mf = 0; mf < 4; ++mf)
      #pragma unroll
      for (int nf = 0; nf < 4; ++nf) acc[mf][nf] = (f32x4){0.f, 0.f, 0.f, 0.f};

    for (int kc = 0; kc < DIMS / 64; ++kc) {
      const int k0 = kc * 64;
      if (ZH) {  // pre-converted fp16 z: straight 64B copy
        const uint4* as = (const uint4*)(zh + (size_t)(m0 + rowS) * DIMS + k0 + ksg);
        uint4* ad = (uint4*)&Ah[rowS * LDH + ksg];
        #pragma unroll
        for (int i = 0; i < 4; ++i) ad[i] = as[i];
      } else {   // convert on the fly
        const float4* src = (const float4*)(z + (size_t)(m0 + rowS) * DIMS + k0 + ksg);
        _Float16* dst = &Ah[rowS * LDH + ksg];
        #pragma unroll
        for (int i = 0; i < 8; ++i) {
          float4 v = src[i];
          union { _Float16 h[4]; uint2 u; } p;
          p.h[0] = (_Float16)v.x; p.h[1] = (_Float16)v.y;
          p.h[2] = (_Float16)v.z; p.h[3] = (_Float16)v.w;
          *(uint2*)(dst + i * 4) = p.u;
        }
      }
      {
        const uint4* bs = (const uint4*)(chs + (size_t)(nt + rowS) * DIMS + k0 + ksg);
        uint4* bd = (uint4*)&Bh[rowS * LDH + ksg];
        #pragma unroll
        for (int i = 0; i < 4; ++i) bd[i] = bs[i];
      }
      __syncthreads();
      #pragma unroll
      for (int ks = 0; ks < 2; ++ks) {
        half8 af[4], bf[4];
        #pragma unroll
        for (int mf = 0; mf < 4; ++mf)
          af[mf] = *(const half8*)&Ah[(wm * 64 + mf * 16 + r) * LDH + ks * 32 + q * 8];
        #pragma unroll
        for (int nf = 0; nf < 4; ++nf)
          bf[nf] = *(const half8*)&Bh[(wn * 64 + nf * 16 + r) * LDH + ks * 32 + q * 8];
        #pragma unroll
        for (int mf = 0; mf < 4; ++mf)
          #pragma unroll
          for (int nf = 0; nf < 4; ++nf)
            acc[mf][nf] = __builtin_amdgcn_mfma_f32_16x16x32_f16(
                af[mf], bf[nf], acc[mf][nf], 0, 0, 0);
      }
      __syncthreads();
    }

    // ---- epilogue on delta = fl(csq - acc*2^-10)  (== sv - zsq, tiny mag,
    //      so fp32 rounding ~1e-8 and fp16 storage ~3e-5 -- margin-safe).
    //      C/D layout: row=q*4+reg, col=r.
    float cs[4];
    #pragma unroll
    for (int nf = 0; nf < 4; ++nf) cs[nf] = csq[nt + wn * 64 + nf * 16 + r];
    float m4[4][4];      // [mf][reg] lane-local min over nf
    #pragma unroll
    for (int mf = 0; mf < 4; ++mf)
      #pragma unroll
      for (int reg = 0; reg < 4; ++reg) {
        float mn = INFINITY;
        #pragma unroll
        for (int nf = 0; nf < 4; ++nf)
          mn = fminf(mn, __fmaf_rn(-0.0009765625f, acc[mf][nf][reg], cs[nf]));
        m4[mf][reg] = mn;
      }
    #pragma unroll
    for (int mf = 0; mf < 4; ++mf)
      #pragma unroll
      for (int reg = 0; reg < 4; ++reg) {
        float v = m4[mf][reg];
        v = fminf(v, __shfl_xor(v, 1, 64));
        v = fminf(v, __shfl_xor(v, 2, 64));
        v = fminf(v, __shfl_xor(v, 4, 64));
        v = fminf(v, __shfl_xor(v, 8, 64));
        m4[mf][reg] = v;
      }
    if (r == 0) {
      #pragma unroll
      for (int mf = 0; mf < 4; ++mf)
        #pragma unroll
        for (int reg = 0; reg < 4; ++reg)
          atomicMin(&rowmin_u[wm * 64 + mf * 16 + q * 4 + reg],
                    __float_as_uint(m4[mf][reg] + 4.0f));  // delta+4 > 0 always
    }
    __syncthreads();   // tile-min now includes this tile, for ALL rows
    #pragma unroll
    for (int mf = 0; mf < 4; ++mf)
      #pragma unroll
      for (int reg = 0; reg < 4; ++reg) {
        const int row = wm * 64 + mf * 16 + q * 4 + reg;
        float thr = __uint_as_float(rowmin_u[row]) - 4.0f + MARGIN;
        #pragma unroll
        for (int nf = 0; nf < 4; ++nf) {
          float d = __fmaf_rn(-0.0009765625f, acc[mf][nf][reg], cs[nf]);
          if (d <= thr) {
            int slot = atomicAdd(&cnt[row], 1);
            if (slot < CAND)
              cand[row * CAND + slot] = pack_ds(d, nt + wn * 64 + nf * 16 + r);
          }
        }
      }
    // ---- periodic compaction: re-filter vs the tightened min so the raw
    //      counter never creeps past CAND (R2's overflow source). Every 4
    //      tiles; drop flag set ONLY if an append was actually discarded.
    if ((t & 3) == 3 || t == (KCODES / 2 / 128 - 1)) {
      __syncthreads();   // all appends for this tile visible
      if (tid < 128) {
        const int raw = cnt[tid];
        const int m = raw < CAND ? raw : CAND;
        if (raw > CAND) dropped[tid] = 1;
        const float thr = __uint_as_float(rowmin_u[tid]) - 4.0f + MARGIN;
        int k = 0;
        for (int i = 0; i < m; ++i) {
          unsigned e = cand[tid * CAND + i];
          if (unpack_d(e) <= thr) cand[tid * CAND + k++] = e;
        }
        cnt[tid] = k;
      }
      __syncthreads();
    }
    // next tile's atomicMin is separated from this append by the kc-loop
    // barriers, so no extra __syncthreads needed here.
  }
  __syncthreads();
  if (tid < 128)
    cnt_g[(size_t)half * N_ROWS + m0 + tid] = dropped[tid] ? (CAND + 1) : cnt[tid];
  for (int i = tid; i < 128 * CAND; i += 256)
    cand_g[((size_t)half * N_ROWS + m0 + i / CAND) * CAND + (i % CAND)] = cand[i];
}

// ---- exact bitwise-np score (R2-verified): dual-panel seq FMA chain ----
__device__ __forceinline__ float exact_q(const float* zr, const float* cr,
                                         float zsr, float csr) {
  float s1 = 0.f;
  for (int k = 0; k < 384; k += 8) {
    float4 a0 = *(const float4*)(zr + k), a1 = *(const float4*)(zr + k + 4);
    float4 b0 = *(const float4*)(cr + k), b1 = *(const float4*)(cr + k + 4);
    s1 = __fmaf_rn(a0.x, b0.x, s1); s1 = __fmaf_rn(a0.y, b0.y, s1);
    s1 = __fmaf_rn(a0.z, b0.z, s1); s1 = __fmaf_rn(a0.w, b0.w, s1);
    s1 = __fmaf_rn(a1.x, b1.x, s1); s1 = __fmaf_rn(a1.y, b1.y, s1);
    s1 = __fmaf_rn(a1.z, b1.z, s1); s1 = __fmaf_rn(a1.w, b1.w, s1);
  }
  float s2 = 0.f;
  for (int k = 384; k < 512; k += 8) {
    float4 a0 = *(const float4*)(zr + k), a1 = *(const float4*)(zr + k + 4);
    float4 b0 = *(const float4*)(cr + k), b1 = *(const float4*)(cr + k + 4);
    s2 = __fmaf_rn(a0.x, b0.x, s2); s2 = __fmaf_rn(a0.y, b0.y, s2);
    s2 = __fmaf_rn(a0.z, b0.z, s2); s2 = __fmaf_rn(a0.w, b0.w, s2);
    s2 = __fmaf_rn(a1.x, b1.x, s2); s2 = __fmaf_rn(a1.y, b1.y, s2);
    s2 = __fmaf_rn(a1.z, b1.z, s2); s2 = __fmaf_rn(a1.w, b1.w, s2);
  }
  float cross = __fadd_rn(s1, s2);                 // fl(S1 + S2)
  return __fadd_rn(__fmaf_rn(-2.f, cross, zsr), csr);
}

// ---- Phase 2a: cross-half merge. Global approx-min filter; singleton rows
//      decided free (competitors provably > margin away); rest -> pair list.
__global__ __launch_bounds__(256) void select_kernel(
    const int* __restrict__ cnt_g, const unsigned* __restrict__ cand_g,
    unsigned long long* __restrict__ best, unsigned* __restrict__ pairs,
    int* __restrict__ meta, int* __restrict__ ovf) {
  const int row  = blockIdx.x * 256 + threadIdx.x;
  const int lane = threadIdx.x & 63;
  const int c0 = cnt_g[row], c1 = cnt_g[N_ROWS + row];
  const bool over = (c0 > CAND) || (c1 > CAND) || (c0 + c1 == 0);
  unsigned long long bkey = ~0ULL;
  int need = 0;
  float thr = 0.f;
  if (!over) {
    float gm = INFINITY;
    for (int j = 0; j < c0; ++j)
      gm = fminf(gm, unpack_d(cand_g[(size_t)row * CAND + j]));
    for (int j = 0; j < c1; ++j)
      gm = fminf(gm, unpack_d(cand_g[(size_t)(N_ROWS + row) * CAND + j]));
    thr = gm + MARGIN;
    int k = 0; unsigned first = 0;
    for (int j = 0; j < c0; ++j) {
      unsigned e = cand_g[(size_t)row * CAND + j];
      if (unpack_d(e) <= thr) { if (k == 0) first = e; ++k; }
    }
    for (int j = 0; j < c1; ++j) {
      unsigned e = cand_g[(size_t)(N_ROWS + row) * CAND + j];
      if (unpack_d(e) <= thr) { if (k == 0) first = e; ++k; }
    }
    if (k == 1) bkey = (unsigned long long)(first & 0x1FFFu);  // decided
    else need = k;
  }
  best[row] = bkey;
  // wave-aggregated worklist allocation (1 atomic per wave)
  int pre = need;
  #pragma unroll
  for (int off = 1; off < 64; off <<= 1) {
    int v = __shfl_up(pre, off, 64);
    if (lane >= off) pre += v;
  }
  int wtot = __shfl(pre, 63, 64);
  int base = 0;
  if (lane == 63 && wtot > 0) base = atomicAdd(&meta[0], wtot);
  base = __shfl(base, 63, 64);
  const int my0 = base + pre - need;              // exclusive prefix
  bool row_ovf = over;
  if (need > 0) {
    if (my0 + need > PAIR_CAP) {
      row_ovf = true;                             // fallback handles this row
      for (int j = 0; j < need; ++j) {            // sentinel allocated slots
        int s = my0 + j;
        if (s < PAIR_CAP) pairs[s] = SENT;
      }
    } else {
      int kk = 0;
      for (int j = 0; j < c0 + c1; ++j) {
        unsigned e = (j < c0) ? cand_g[(size_t)row * CAND + j]
                              : cand_g[(size_t)(N_ROWS + row) * CAND + (j - c0)];
        if (unpack_d(e) <= thr)
          pairs[my0 + kk++] = ((unsigned)row << 13) | (e & 0x1FFFu);
      }
    }
  }
  if (row_ovf) { int s = atomicAdd(&meta[1], 1); ovf[s] = row; }
}

// ---- Phase 2b: dense exact rescore, one lane per (row,code) pair.
//      d2 > 0 always (zsq ~ 512) so uint order == float order; packed key
//      (q_bits<<32)|code -> atomicMin = argmin with lowest-index tie-break.
__global__ __launch_bounds__(256) void pairs_kernel(
    const float* __restrict__ z, const float* __restrict__ cb,
    const float* __restrict__ zsq, const float* __restrict__ csq,
    const unsigned* __restrict__ pairs, const int* __restrict__ meta,
    unsigned long long* __restrict__ best) {
  int n = meta[0];
  if (n > PAIR_CAP) n = PAIR_CAP;
  const int i = blockIdx.x * 256 + threadIdx.x;
  if (i >= n) return;
  const unsigned p = pairs[i];
  if (p == SENT) return;                          // unfilled overflow slot
  const int row = (int)(p >> 13), code = (int)(p & 8191u);
  const float qv = exact_q(z + (size_t)row * DIMS, cb + (size_t)code * DIMS,
                           zsq[row], csq[code]);
  const unsigned long long key =
      ((unsigned long long)__float_as_uint(qv) << 32) | (unsigned)code;
  atomicMin(&best[row], key);
}

// ---- Phase 2c: overflow net, one BLOCK per row (R3 rewrite).
//      Pass A: coalesced approx scan (8-lane groups, fp32 tree dot), scores
//              to LDS, block min.  |approx - (exact_q - zsq)| < ~1e-4:
//              tree-vs-chain fp32 dot diff ~1e-5 + zsq-add rounding ~6e-5.
//      Pass B: exact_q only for codes within min + 5e-4 -> atomicMin.
__global__ __launch_bounds__(256) void fallback_kernel(
    const float* __restrict__ z, const float* __restrict__ cb,
    const float* __restrict__ zsq, const float* __restrict__ csq,
    const int* __restrict__ ovf, const int* __restrict__ meta,
    unsigned long long* __restrict__ best) {
  __shared__ float sc[KCODES];     // 32 KB approx deltas
  __shared__ float zrow[DIMS];     // 2 KB
  __shared__ unsigned bmin;
  const int n = meta[1];
  for (int wi = blockIdx.x; wi < n; wi += gridDim.x) {
    const int row = ovf[wi];
    for (int i = threadIdx.x; i < DIMS; i += 256)
      zrow[i] = z[(size_t)row * DIMS + i];
    if (threadIdx.x == 0) bmin = 0x7f800000u;
    __syncthreads();
    const int g = threadIdx.x >> 3;       // 32 groups of 8 lanes
    const int j = threadIdx.x & 7;
    float lmin = INFINITY;
    for (int c = g; c < KCODES; c += 32) {
      const float* cr = cb + (size_t)c * DIMS;
      float s = 0.f;
      #pragma unroll
      for (int i = 0; i < 16; ++i) {      // 64 dims per lane, 128B/group/step
        float4 a = *(const float4*)(&zrow[j * 4 + i * 32]);
        float4 b = *(const float4*)(cr + j * 4 + i * 32);
        s = __fmaf_rn(a.x, b.x, s); s = __fmaf_rn(a.y, b.y, s);
        s = __fmaf_rn(a.z, b.z, s); s = __fmaf_rn(a.w, b.w, s);
      }
      s += __shfl_xor(s, 1, 64);          // butterfly within 8-lane group
      s += __shfl_xor(s, 2, 64);
      s += __shfl_xor(s, 4, 64);
      float d = __fmaf_rn(-2.f, s, csq[c]);
      if (j == 0) sc[c] = d;
      lmin = fminf(lmin, d);
    }
    atomicMin(&bmin, __float_as_uint(lmin + 4.0f));   // delta+4 > 0
    __syncthreads();
    const float thr = __uint_as_float(bmin) - 4.0f + 5e-4f;
    const float zsr = zsq[row];
    const float* zr = z + (size_t)row * DIMS;
    for (int c = threadIdx.x; c < KCODES; c += 256) {
      if (sc[c] <= thr) {
        float qv = exact_q(zr, cb + (size_t)c * DIMS, zsr, csq[c]);
        unsigned long long key =
            ((unsigned long long)__float_as_uint(qv) << 32) | (unsigned)c;
        atomicMin(&best[row], key);
      }
    }
    __syncthreads();   // before next row reuses LDS
  }
}

// ---- Phase 2d: coalesced gather of winner rows + index write ----
__global__ __launch_bounds__(256) void gather_kernel(
    const float* __restrict__ cb, const unsigned long long* __restrict__ best,
    float* __restrict__ zq, float* __restrict__ idx_out) {
  const int wave = threadIdx.x >> 6, lane = threadIdx.x & 63;
  const int row = blockIdx.x * 4 + wave;
  const int code = (int)(unsigned)(best[row] & 0xFFFFFFFFu);
  if (lane == 0) idx_out[row] = (float)code;
  const float4* cbv = (const float4*)(cb + (size_t)code * DIMS);
  float4* zqv = (float4*)(zq + (size_t)row * DIMS);
  zqv[lane]      = cbv[lane];
  zqv[lane + 64] = cbv[lane + 64];
}

extern "C" void kernel_launch(void* const* d_in, const int* in_sizes, int n_in,
                              void* d_out, int out_size, void* d_ws, size_t ws_size,
                              hipStream_t stream) {
  const float* z  = (const float*)d_in[0];
  const float* cb = (const float*)d_in[1];
  float* out     = (float*)d_out;
  float* zq      = out;
  float* idx_out = out + (size_t)N_ROWS * DIMS;

  // workspace layout (all chunks 256B-multiples)
  char* w = (char*)d_ws;
  _Float16* cbh = (_Float16*)w;            w += (size_t)KCODES * DIMS * 2;   // 8 MB
  float* zsq = (float*)w;                  w += (size_t)N_ROWS * 4;          // 128 KB
  float* csq = (float*)w;                  w += (size_t)KCODES * 4;          // 32 KB
  int* cnt_g = (int*)w;                    w += (size_t)2 * N_ROWS * 4;      // 256 KB
  unsigned* cand_g = (unsigned*)w;         w += (size_t)2 * N_ROWS * CAND * 4; // 8 MB
  unsigned long long* best = (unsigned long long*)w; w += (size_t)N_ROWS * 8;  // 256 KB
  unsigned* pairs = (unsigned*)w;          w += (size_t)PAIR_CAP * 4;        // 1 MB
  int* meta = (int*)w;                     w += 256;                         // counters
  int* ovf = (int*)w;                      w += (size_t)N_ROWS * 4;          // 128 KB
  _Float16* zh = (_Float16*)w;             w += (size_t)N_ROWS * DIMS * 2;   // 32 MB
  bool use_zh = ((size_t)(w - (char*)d_ws) <= ws_size);

  hipMemsetAsync(meta, 0, 256, stream);

  rowsq_kernel<<<N_ROWS / 4, 256, 0, stream>>>(z, zsq);
  rowsq_kernel<<<KCODES / 4, 256, 0, stream>>>(cb, csq);
  cvt_cb_kernel<<<KCODES * DIMS / 1024, 256, 0, stream>>>(cb, cbh);
  if (use_zh) {
    cvt_z_kernel<<<N_ROWS * DIMS / 1024, 256, 0, stream>>>(z, zh);
    vq_mfma_kernel<true><<<(N_ROWS / 128) * 2, 256, 0, stream>>>(
        z, zh, cbh, csq, cand_g, cnt_g);
  } else {
    vq_mfma_kernel<false><<<(N_ROWS / 128) * 2, 256, 0, stream>>>(
        z, nullptr, cbh, csq, cand_g, cnt_g);
  }
  select_kernel<<<N_ROWS / 256, 256, 0, stream>>>(cnt_g, cand_g, best, pairs,
                                                  meta, ovf);
  pairs_kernel<<<PAIR_CAP / 256, 256, 0, stream>>>(z, cb, zsq, csq, pairs,
                                                   meta, best);
  fallback_kernel<<<512, 256, 0, stream>>>(z, cb, zsq, csq, ovf, meta, best);
  gather_kernel<<<N_ROWS / 4, 256, 0, stream>>>(cb, best, zq, idx_out);
}